// Round 1
// baseline (1633.194 us; speedup 1.0000x reference)
//
#include <hip/hip_runtime.h>
#include <math.h>

#define INCH 128
#define DH 64     // d*h
#define H  32
#define D  2
#define LAYERS 4
#define OUTC 32

__device__ __forceinline__ float eluf(float v) { return v > 0.f ? v : expm1f(v); }

// X = elu(xin @ W1^T + b1) ; X:[N,64]
__global__ void k_mlp1(const float* __restrict__ xin, const float* __restrict__ W1,
                       const float* __restrict__ b1, float* __restrict__ X, int N) {
    __shared__ float Ws[DH * 129];   // padded rows: Ws[oc*129 + k]
    __shared__ float xs[4][INCH];
    for (int t = threadIdx.x; t < DH * INCH; t += blockDim.x)
        Ws[(t >> 7) * 129 + (t & 127)] = W1[t];
    int node0 = blockIdx.x * 4;
    for (int t = threadIdx.x; t < 4 * INCH; t += blockDim.x) {
        int nn = t >> 7, k = t & 127;
        int node = node0 + nn;
        xs[nn][k] = (node < N) ? xin[(size_t)node * INCH + k] : 0.f;
    }
    __syncthreads();
    int nn = threadIdx.x >> 6;
    int oc = threadIdx.x & 63;
    int node = node0 + nn;
    if (node >= N) return;
    float acc = b1[oc];
    const float* wr = Ws + oc * 129;
    #pragma unroll 16
    for (int k = 0; k < INCH; ++k) acc += xs[nn][k] * wr[k];
    X[(size_t)node * DH + oc] = eluf(acc);
}

// wave (64 lanes) per edge: F[e,:] = tanh(Wsheaf_l @ [x_src ; x_dst]); DG[src,:] += F*F
__global__ void k_sheaf(const float* __restrict__ X, const int* __restrict__ src,
                        const int* __restrict__ dst, const float* __restrict__ Wsl,
                        float* __restrict__ F, float* __restrict__ DG, int E) {
    int wid = (blockIdx.x * blockDim.x + threadIdx.x) >> 6;
    int lane = threadIdx.x & 63;
    if (wid >= E) return;
    int si = src[wid], di = dst[wid];
    float a = X[(size_t)si * DH + lane];
    float b = X[(size_t)di * DH + lane];
    float p0 = a * Wsl[lane]       + b * Wsl[64 + lane];
    float p1 = a * Wsl[128 + lane] + b * Wsl[192 + lane];
    #pragma unroll
    for (int off = 32; off; off >>= 1) {
        p0 += __shfl_down(p0, off);
        p1 += __shfl_down(p1, off);
    }
    if (lane == 0) {
        float f0 = tanhf(p0), f1 = tanhf(p1);
        F[(size_t)wid * 2]     = f0;
        F[(size_t)wid * 2 + 1] = f1;
        atomicAdd(&DG[(size_t)si * 2],     f0 * f0);
        atomicAdd(&DG[(size_t)si * 2 + 1], f1 * f1);
    }
}

// thread per edge: OFFW = -F * F[rev] * rsqrt(DG[src]+1) * rsqrt(DG[dst]+1)
__global__ void k_offw(const float* __restrict__ F, const float* __restrict__ DG,
                       const int* __restrict__ src, const int* __restrict__ dst,
                       float* __restrict__ OFFW, int E) {
    int e = blockIdx.x * blockDim.x + threadIdx.x;
    if (e >= E) return;
    int EU = E >> 1;
    int r = (e < EU) ? e + EU : e - EU;
    int si = src[e], di = dst[e];
    float2 f  = *(const float2*)(F + (size_t)e * 2);
    float2 fr = *(const float2*)(F + (size_t)r * 2);
    float2 gs = *(const float2*)(DG + (size_t)si * 2);
    float2 gd = *(const float2*)(DG + (size_t)di * 2);
    float2 o;
    o.x = -f.x * fr.x * rsqrtf(gs.x + 1.f) * rsqrtf(gd.x + 1.f);
    o.y = -f.y * fr.y * rsqrtf(gs.y + 1.f) * rsqrtf(gd.y + 1.f);
    *(float2*)(OFFW + (size_t)e * 2) = o;
}

// per node: XW[i, s', c] = sum_{s,c'} Wl[s',s] * X[i,s,c'] * Wr[c,c']
__global__ void k_lr(const float* __restrict__ X, const float* __restrict__ Wl,
                     const float* __restrict__ Wr, float* __restrict__ XW, int N) {
    __shared__ float wrS[H * 33];   // padded: wrS[c*33 + cp]
    __shared__ float xs[4][DH];
    for (int t = threadIdx.x; t < H * H; t += blockDim.x)
        wrS[(t >> 5) * 33 + (t & 31)] = Wr[t];
    int node0 = blockIdx.x * 4;
    {
        int t = threadIdx.x;
        int nn = t >> 6, cc = t & 63;
        int node = node0 + nn;
        xs[nn][cc] = (node < N) ? X[(size_t)node * DH + cc] : 0.f;
    }
    __syncthreads();
    int nn = threadIdx.x >> 6;
    int node = node0 + nn;
    if (node >= N) return;
    int sc = threadIdx.x & 63;
    int sp = sc >> 5;      // output stalk s'
    int c  = sc & 31;      // output channel
    float wl0 = Wl[sp * 2 + 0], wl1 = Wl[sp * 2 + 1];
    float acc = 0.f;
    #pragma unroll
    for (int cp = 0; cp < H; ++cp) {
        float mixed = wl0 * xs[nn][cp] + wl1 * xs[nn][32 + cp];
        acc += mixed * wrS[c * 33 + cp];
    }
    XW[(size_t)node * DH + sp * 32 + c] = acc;
}

// wave per edge: Y[src, s, c] += OFFW[e,s] * XW[dst, s, c]
__global__ void k_spmm(const float* __restrict__ XW, const float* __restrict__ OFFW,
                       const int* __restrict__ src, const int* __restrict__ dst,
                       float* __restrict__ Y, int E) {
    int wid = (blockIdx.x * blockDim.x + threadIdx.x) >> 6;
    int lane = threadIdx.x & 63;
    if (wid >= E) return;
    int si = src[wid], di = dst[wid];
    float w = OFFW[(size_t)wid * 2 + (lane >> 5)];
    float v = XW[(size_t)di * DH + lane];
    atomicAdd(&Y[(size_t)si * DH + lane], w * v);
}

// per element: X = coeff_s * X - elu(diagw*XW + Y)
__global__ void k_fin(const float* __restrict__ Y, const float* __restrict__ XW,
                      const float* __restrict__ DG, const float* __restrict__ eps_l,
                      float* __restrict__ X, int total) {
    int idx = blockIdx.x * blockDim.x + threadIdx.x;
    if (idx >= total) return;
    int node = idx >> 6;
    int s = (idx >> 5) & 1;
    float dg = DG[(size_t)node * 2 + s];
    float diagw = dg / (dg + 1.f);
    float v = diagw * XW[idx] + Y[idx];
    float coeff = 1.f + tanhf(eps_l[s]);
    X[idx] = coeff * X[idx] - eluf(v);
}

// out = X @ W2^T + b2 ; [N,32]
__global__ void k_out(const float* __restrict__ X, const float* __restrict__ W2,
                      const float* __restrict__ b2, float* __restrict__ out, int N) {
    __shared__ float w2S[OUTC * 65];  // padded: w2S[oc*65 + k]
    __shared__ float xs[8][DH];
    for (int t = threadIdx.x; t < OUTC * DH; t += blockDim.x)
        w2S[(t >> 6) * 65 + (t & 63)] = W2[t];
    int node0 = blockIdx.x * 8;
    for (int t = threadIdx.x; t < 8 * DH; t += blockDim.x) {
        int nn = t >> 6, k = t & 63;
        int node = node0 + nn;
        xs[nn][k] = (node < N) ? X[(size_t)node * DH + k] : 0.f;
    }
    __syncthreads();
    int nn = threadIdx.x >> 5;
    int oc = threadIdx.x & 31;
    int node = node0 + nn;
    if (node >= N) return;
    float acc = b2[oc];
    #pragma unroll
    for (int k = 0; k < DH; ++k) acc += xs[nn][k] * w2S[oc * 65 + k];
    out[(size_t)node * OUTC + oc] = acc;
}

extern "C" void kernel_launch(void* const* d_in, const int* in_sizes, int n_in,
                              void* d_out, int out_size, void* d_ws, size_t ws_size,
                              hipStream_t stream) {
    const float* xin    = (const float*)d_in[0];
    const int*   ei     = (const int*)d_in[1];
    const float* W1     = (const float*)d_in[2];
    const float* b1     = (const float*)d_in[3];
    const float* Wsheaf = (const float*)d_in[4];
    const float* Wleft  = (const float*)d_in[5];
    const float* Wright = (const float*)d_in[6];
    const float* eps    = (const float*)d_in[7];
    const float* W2     = (const float*)d_in[8];
    const float* b2     = (const float*)d_in[9];
    float* out = (float*)d_out;

    int N = in_sizes[0] / INCH;
    int E = in_sizes[1] / 2;
    const int* src = ei;
    const int* dst = ei + E;

    size_t off = 0;
    auto alloc = [&](size_t nfloats) {
        float* p = (float*)((char*)d_ws + off);
        off += ((nfloats * 4 + 255) / 256) * 256;
        return p;
    };
    float* X    = alloc((size_t)N * DH);
    float* XW   = alloc((size_t)N * DH);
    float* Y    = alloc((size_t)N * DH);
    float* F    = alloc((size_t)E * 2);
    float* OFFW = alloc((size_t)E * 2);
    float* DG   = alloc((size_t)N * 2);

    k_mlp1<<<(N + 3) / 4, 256, 0, stream>>>(xin, W1, b1, X, N);

    for (int l = 0; l < LAYERS; ++l) {
        hipMemsetAsync(DG, 0, (size_t)N * 2 * sizeof(float), stream);
        k_sheaf<<<(E + 3) / 4, 256, 0, stream>>>(X, src, dst, Wsheaf + l * 2 * INCH, F, DG, E);
        k_offw<<<(E + 255) / 256, 256, 0, stream>>>(F, DG, src, dst, OFFW, E);
        k_lr<<<(N + 3) / 4, 256, 0, stream>>>(X, Wleft + l * 4, Wright + l * H * H, XW, N);
        hipMemsetAsync(Y, 0, (size_t)N * DH * sizeof(float), stream);
        k_spmm<<<(E + 3) / 4, 256, 0, stream>>>(XW, OFFW, src, dst, Y, E);
        k_fin<<<(N * DH + 255) / 256, 256, 0, stream>>>(Y, XW, DG, eps + l * 2, X, N * DH);
    }

    k_out<<<(N + 7) / 8, 256, 0, stream>>>(X, W2, b2, out, N);
}

// Round 2
// 1265.510 us; speedup vs baseline: 1.2905x; 1.2905x over previous
//
#include <hip/hip_runtime.h>
#include <math.h>

#define INCH 128
#define DH 64     // d*h
#define H  32
#define D  2
#define LAYERS 4
#define OUTC 32

__device__ __forceinline__ float eluf(float v) { return v > 0.f ? v : expm1f(v); }

// X = elu(xin @ W1^T + b1) ; X:[N,64]
__global__ void k_mlp1(const float* __restrict__ xin, const float* __restrict__ W1,
                       const float* __restrict__ b1, float* __restrict__ X, int N) {
    __shared__ float Ws[DH * 129];   // padded rows: Ws[oc*129 + k]
    __shared__ float xs[4][INCH];
    for (int t = threadIdx.x; t < DH * INCH; t += blockDim.x)
        Ws[(t >> 7) * 129 + (t & 127)] = W1[t];
    int node0 = blockIdx.x * 4;
    for (int t = threadIdx.x; t < 4 * INCH; t += blockDim.x) {
        int nn = t >> 7, k = t & 127;
        int node = node0 + nn;
        xs[nn][k] = (node < N) ? xin[(size_t)node * INCH + k] : 0.f;
    }
    __syncthreads();
    int nn = threadIdx.x >> 6;
    int oc = threadIdx.x & 63;
    int node = node0 + nn;
    if (node >= N) return;
    float acc = b1[oc];
    const float* wr = Ws + oc * 129;
    #pragma unroll 16
    for (int k = 0; k < INCH; ++k) acc += xs[nn][k] * wr[k];
    X[(size_t)node * DH + oc] = eluf(acc);
}

// ---------------- CSR build (by src) ----------------
__global__ void k_hist(const int* __restrict__ src, int* __restrict__ deg, int E) {
    int e = blockIdx.x * blockDim.x + threadIdx.x;
    if (e < E) atomicAdd(&deg[src[e]], 1);
}

// single-block exclusive scan: rowptr[0..N], input deg[0..N-1]
__global__ void k_scan(const int* __restrict__ deg, int* __restrict__ rowptr, int N) {
    __shared__ int wsum[16];
    __shared__ int woff[16];
    __shared__ int carry_s;
    int tid = threadIdx.x;
    int lane = tid & 63, wid = tid >> 6;
    if (tid == 0) carry_s = 0;
    __syncthreads();
    for (int base = 0; base < N; base += 1024) {
        int i = base + tid;
        int v = (i < N) ? deg[i] : 0;
        int incl = v;
        #pragma unroll
        for (int ofs = 1; ofs < 64; ofs <<= 1) {
            int t = __shfl_up(incl, ofs);
            if (lane >= ofs) incl += t;
        }
        if (lane == 63) wsum[wid] = incl;
        __syncthreads();
        if (wid == 0 && lane < 16) {
            int w = wsum[lane];
            int wi = w;
            #pragma unroll
            for (int ofs = 1; ofs < 16; ofs <<= 1) {
                int t = __shfl_up(wi, ofs);
                if (lane >= ofs) wi += t;
            }
            woff[lane] = wi - w;  // exclusive within chunk
        }
        __syncthreads();
        int carry = carry_s;
        int excl = carry + woff[wid] + incl - v;
        if (i < N) rowptr[i] = excl;
        if (i == N - 1) rowptr[N] = excl + v;
        __syncthreads();
        if (tid == 1023) carry_s = carry + woff[15] + wsum[15];
        __syncthreads();
    }
}

__global__ void k_initcur(const int* __restrict__ rowptr, int* __restrict__ cur, int N) {
    int i = blockIdx.x * blockDim.x + threadIdx.x;
    if (i < N) cur[i] = rowptr[i];
}

__global__ void k_scatter(const int* __restrict__ src, int* __restrict__ cur,
                          int* __restrict__ perm, int E) {
    int e = blockIdx.x * blockDim.x + threadIdx.x;
    if (e >= E) return;
    int pos = atomicAdd(&cur[src[e]], 1);
    perm[pos] = e;
}

// ---------------- per-layer kernels ----------------

// wave per node: P[i,s] = sum_k Wsl[s*128+k] X[i,k] ; Q[i,s] = sum_k Wsl[s*128+64+k] X[i,k]
__global__ void k_pq(const float* __restrict__ X, const float* __restrict__ Wsl,
                     float* __restrict__ P, float* __restrict__ Q, int N) {
    int wid = (blockIdx.x * blockDim.x + threadIdx.x) >> 6;
    int lane = threadIdx.x & 63;
    if (wid >= N) return;
    float x = X[(size_t)wid * DH + lane];
    float p0 = x * Wsl[lane];
    float q0 = x * Wsl[64 + lane];
    float p1 = x * Wsl[128 + lane];
    float q1 = x * Wsl[192 + lane];
    #pragma unroll
    for (int ofs = 32; ofs; ofs >>= 1) {
        p0 += __shfl_xor(p0, ofs);
        q0 += __shfl_xor(q0, ofs);
        p1 += __shfl_xor(p1, ofs);
        q1 += __shfl_xor(q1, ofs);
    }
    if (lane == 0) {
        *(float2*)(P + (size_t)wid * 2) = make_float2(p0, p1);
        *(float2*)(Q + (size_t)wid * 2) = make_float2(q0, q1);
    }
}

// thread per edge: F[e,s] = tanh(P[src,s] + Q[dst,s]); DG[src,s] += F^2
__global__ void k_edgeF(const float* __restrict__ P, const float* __restrict__ Q,
                        const int* __restrict__ src, const int* __restrict__ dst,
                        float* __restrict__ F, float* __restrict__ DG, int E) {
    int e = blockIdx.x * blockDim.x + threadIdx.x;
    if (e >= E) return;
    int si = src[e], di = dst[e];
    float2 p = *(const float2*)(P + (size_t)si * 2);
    float2 q = *(const float2*)(Q + (size_t)di * 2);
    float f0 = tanhf(p.x + q.x), f1 = tanhf(p.y + q.y);
    *(float2*)(F + (size_t)e * 2) = make_float2(f0, f1);
    atomicAdd(&DG[(size_t)si * 2],     f0 * f0);
    atomicAdd(&DG[(size_t)si * 2 + 1], f1 * f1);
}

// thread per edge: OFFW = -F * F[rev] * rsqrt(DG[src]+1) * rsqrt(DG[dst]+1)
__global__ void k_offw(const float* __restrict__ F, const float* __restrict__ DG,
                       const int* __restrict__ src, const int* __restrict__ dst,
                       float* __restrict__ OFFW, int E) {
    int e = blockIdx.x * blockDim.x + threadIdx.x;
    if (e >= E) return;
    int EU = E >> 1;
    int r = (e < EU) ? e + EU : e - EU;
    int si = src[e], di = dst[e];
    float2 f  = *(const float2*)(F + (size_t)e * 2);
    float2 fr = *(const float2*)(F + (size_t)r * 2);
    float2 gs = *(const float2*)(DG + (size_t)si * 2);
    float2 gd = *(const float2*)(DG + (size_t)di * 2);
    float2 o;
    o.x = -f.x * fr.x * rsqrtf(gs.x + 1.f) * rsqrtf(gd.x + 1.f);
    o.y = -f.y * fr.y * rsqrtf(gs.y + 1.f) * rsqrtf(gd.y + 1.f);
    *(float2*)(OFFW + (size_t)e * 2) = o;
}

// per node: XW[i, s', c] = sum_{s,c'} Wl[s',s] * X[i,s,c'] * Wr[c,c']
__global__ void k_lr(const float* __restrict__ X, const float* __restrict__ Wl,
                     const float* __restrict__ Wr, float* __restrict__ XW, int N) {
    __shared__ float wrS[H * 33];   // padded: wrS[c*33 + cp]
    __shared__ float xs[4][DH];
    for (int t = threadIdx.x; t < H * H; t += blockDim.x)
        wrS[(t >> 5) * 33 + (t & 31)] = Wr[t];
    int node0 = blockIdx.x * 4;
    {
        int t = threadIdx.x;
        int nn = t >> 6, cc = t & 63;
        int node = node0 + nn;
        xs[nn][cc] = (node < N) ? X[(size_t)node * DH + cc] : 0.f;
    }
    __syncthreads();
    int nn = threadIdx.x >> 6;
    int node = node0 + nn;
    if (node >= N) return;
    int sc = threadIdx.x & 63;
    int sp = sc >> 5;      // output stalk s'
    int c  = sc & 31;      // output channel
    float wl0 = Wl[sp * 2 + 0], wl1 = Wl[sp * 2 + 1];
    float acc = 0.f;
    #pragma unroll
    for (int cp = 0; cp < H; ++cp) {
        float mixed = wl0 * xs[nn][cp] + wl1 * xs[nn][32 + cp];
        acc += mixed * wrS[c * 33 + cp];
    }
    XW[(size_t)node * DH + sp * 32 + c] = acc;
}

// wave per node: y = diagw*XW[i] + sum_{e in CSR[i]} OFFW[e]*XW[dst[e]]; X = coeff*X - elu(y)
__global__ void k_spmm_fin(const float* __restrict__ XW, const float* __restrict__ OFFW,
                           const int* __restrict__ rowptr, const int* __restrict__ perm,
                           const int* __restrict__ dst, const float* __restrict__ DG,
                           const float* __restrict__ eps_l, float* __restrict__ X, int N) {
    int wid = (blockIdx.x * blockDim.x + threadIdx.x) >> 6;
    int lane = threadIdx.x & 63;
    if (wid >= N) return;
    int s = lane >> 5;
    float dg = DG[(size_t)wid * 2 + s];
    float acc = dg / (dg + 1.f) * XW[(size_t)wid * DH + lane];
    int pos = rowptr[wid], end = rowptr[wid + 1];
    for (; pos < end; ++pos) {
        int e = perm[pos];
        int di = dst[e];
        float w = OFFW[(size_t)e * 2 + s];
        acc += w * XW[(size_t)di * DH + lane];
    }
    float coeff = 1.f + tanhf(eps_l[s]);
    size_t idx = (size_t)wid * DH + lane;
    X[idx] = coeff * X[idx] - eluf(acc);
}

// out = X @ W2^T + b2 ; [N,32]
__global__ void k_out(const float* __restrict__ X, const float* __restrict__ W2,
                      const float* __restrict__ b2, float* __restrict__ out, int N) {
    __shared__ float w2S[OUTC * 65];  // padded: w2S[oc*65 + k]
    __shared__ float xs[8][DH];
    for (int t = threadIdx.x; t < OUTC * DH; t += blockDim.x)
        w2S[(t >> 6) * 65 + (t & 63)] = W2[t];
    int node0 = blockIdx.x * 8;
    for (int t = threadIdx.x; t < 8 * DH; t += blockDim.x) {
        int nn = t >> 6, k = t & 63;
        int node = node0 + nn;
        xs[nn][k] = (node < N) ? X[(size_t)node * DH + k] : 0.f;
    }
    __syncthreads();
    int nn = threadIdx.x >> 5;
    int oc = threadIdx.x & 31;
    int node = node0 + nn;
    if (node >= N) return;
    float acc = b2[oc];
    #pragma unroll
    for (int k = 0; k < DH; ++k) acc += xs[nn][k] * w2S[oc * 65 + k];
    out[(size_t)node * OUTC + oc] = acc;
}

extern "C" void kernel_launch(void* const* d_in, const int* in_sizes, int n_in,
                              void* d_out, int out_size, void* d_ws, size_t ws_size,
                              hipStream_t stream) {
    const float* xin    = (const float*)d_in[0];
    const int*   ei     = (const int*)d_in[1];
    const float* W1     = (const float*)d_in[2];
    const float* b1     = (const float*)d_in[3];
    const float* Wsheaf = (const float*)d_in[4];
    const float* Wleft  = (const float*)d_in[5];
    const float* Wright = (const float*)d_in[6];
    const float* eps    = (const float*)d_in[7];
    const float* W2     = (const float*)d_in[8];
    const float* b2     = (const float*)d_in[9];
    float* out = (float*)d_out;

    int N = in_sizes[0] / INCH;
    int E = in_sizes[1] / 2;
    const int* src = ei;
    const int* dst = ei + E;

    size_t off = 0;
    auto alloc = [&](size_t nelems) {
        char* p = (char*)d_ws + off;
        off += ((nelems * 4 + 255) / 256) * 256;
        return p;
    };
    float* X      = (float*)alloc((size_t)N * DH);
    float* XW     = (float*)alloc((size_t)N * DH);
    float* F      = (float*)alloc((size_t)E * 2);
    float* OFFW   = (float*)alloc((size_t)E * 2);
    float* DG     = (float*)alloc((size_t)N * 2);
    float* P      = (float*)alloc((size_t)N * 2);
    float* Q      = (float*)alloc((size_t)N * 2);
    int*   deg    = (int*)alloc((size_t)N);
    int*   rowptr = (int*)alloc((size_t)N + 1);
    int*   cur    = (int*)alloc((size_t)N);
    int*   perm   = (int*)alloc((size_t)E);

    // ---- CSR by src (once per call) ----
    hipMemsetAsync(deg, 0, (size_t)N * sizeof(int), stream);
    k_hist<<<(E + 255) / 256, 256, 0, stream>>>(src, deg, E);
    k_scan<<<1, 1024, 0, stream>>>(deg, rowptr, N);
    k_initcur<<<(N + 255) / 256, 256, 0, stream>>>(rowptr, cur, N);
    k_scatter<<<(E + 255) / 256, 256, 0, stream>>>(src, cur, perm, E);

    k_mlp1<<<(N + 3) / 4, 256, 0, stream>>>(xin, W1, b1, X, N);

    for (int l = 0; l < LAYERS; ++l) {
        hipMemsetAsync(DG, 0, (size_t)N * 2 * sizeof(float), stream);
        k_pq<<<(N + 3) / 4, 256, 0, stream>>>(X, Wsheaf + l * 2 * INCH, P, Q, N);
        k_edgeF<<<(E + 255) / 256, 256, 0, stream>>>(P, Q, src, dst, F, DG, E);
        k_offw<<<(E + 255) / 256, 256, 0, stream>>>(F, DG, src, dst, OFFW, E);
        k_lr<<<(N + 3) / 4, 256, 0, stream>>>(X, Wleft + l * 4, Wright + l * H * H, XW, N);
        k_spmm_fin<<<(N + 3) / 4, 256, 0, stream>>>(XW, OFFW, rowptr, perm, dst, DG,
                                                    eps + l * 2, X, N);
    }

    k_out<<<(N + 7) / 8, 256, 0, stream>>>(X, W2, b2, out, N);
}

// Round 3
// 992.974 us; speedup vs baseline: 1.6447x; 1.2745x over previous
//
#include <hip/hip_runtime.h>
#include <math.h>

#define INCH 128
#define DH 64     // d*h
#define H  32
#define D  2
#define LAYERS 4
#define OUTC 32

__device__ __forceinline__ float eluf(float v) { return v > 0.f ? v : expm1f(v); }
__device__ __forceinline__ float bf2f(unsigned short u) {
    union { unsigned int i; float f; } c; c.i = ((unsigned int)u) << 16; return c.f;
}
__device__ __forceinline__ unsigned short f2bf(float f) {
    union { float f; unsigned int i; } c; c.f = f;
    unsigned int lsb = (c.i >> 16) & 1;
    c.i += 0x7fff + lsb;            // round-to-nearest-even
    return (unsigned short)(c.i >> 16);
}

// X = elu(xin @ W1^T + b1); fused P/Q for layer 0
__global__ void k_mlp1_pq(const float* __restrict__ xin, const float* __restrict__ W1,
                          const float* __restrict__ b1, const float* __restrict__ Ws0,
                          float* __restrict__ X, float2* __restrict__ P,
                          float2* __restrict__ Q, int N) {
    __shared__ float Ws[DH * 129];   // padded rows: Ws[oc*129 + k]
    __shared__ float xs[4][INCH];
    for (int t = threadIdx.x; t < DH * INCH; t += blockDim.x)
        Ws[(t >> 7) * 129 + (t & 127)] = W1[t];
    int node0 = blockIdx.x * 4;
    for (int t = threadIdx.x; t < 4 * INCH; t += blockDim.x) {
        int nn = t >> 7, k = t & 127;
        int node = node0 + nn;
        xs[nn][k] = (node < N) ? xin[(size_t)node * INCH + k] : 0.f;
    }
    __syncthreads();
    int nn = threadIdx.x >> 6;
    int lane = threadIdx.x & 63;
    int node = node0 + nn;
    if (node >= N) return;
    float acc = b1[lane];
    const float* wr = Ws + lane * 129;
    #pragma unroll 16
    for (int k = 0; k < INCH; ++k) acc += xs[nn][k] * wr[k];
    float v = eluf(acc);
    X[(size_t)node * DH + lane] = v;
    // fused P/Q (layer 0)
    float p0 = v * Ws0[lane], q0 = v * Ws0[64 + lane];
    float p1 = v * Ws0[128 + lane], q1 = v * Ws0[192 + lane];
    #pragma unroll
    for (int ofs = 32; ofs; ofs >>= 1) {
        p0 += __shfl_xor(p0, ofs); q0 += __shfl_xor(q0, ofs);
        p1 += __shfl_xor(p1, ofs); q1 += __shfl_xor(q1, ofs);
    }
    if (lane == 0) { P[node] = make_float2(p0, p1); Q[node] = make_float2(q0, q1); }
}

// ---------------- CSR build (by src) ----------------
__global__ void k_hist(const int* __restrict__ src, int* __restrict__ deg, int E) {
    int e = blockIdx.x * blockDim.x + threadIdx.x;
    if (e < E) atomicAdd(&deg[src[e]], 1);
}

__global__ void k_scan(const int* __restrict__ deg, int* __restrict__ rowptr, int N) {
    __shared__ int wsum[16];
    __shared__ int woff[16];
    __shared__ int carry_s;
    int tid = threadIdx.x;
    int lane = tid & 63, wid = tid >> 6;
    if (tid == 0) carry_s = 0;
    __syncthreads();
    for (int base = 0; base < N; base += 1024) {
        int i = base + tid;
        int v = (i < N) ? deg[i] : 0;
        int incl = v;
        #pragma unroll
        for (int ofs = 1; ofs < 64; ofs <<= 1) {
            int t = __shfl_up(incl, ofs);
            if (lane >= ofs) incl += t;
        }
        if (lane == 63) wsum[wid] = incl;
        __syncthreads();
        if (wid == 0 && lane < 16) {
            int w = wsum[lane];
            int wi = w;
            #pragma unroll
            for (int ofs = 1; ofs < 16; ofs <<= 1) {
                int t = __shfl_up(wi, ofs);
                if (lane >= ofs) wi += t;
            }
            woff[lane] = wi - w;
        }
        __syncthreads();
        int carry = carry_s;
        int excl = carry + woff[wid] + incl - v;
        if (i < N) rowptr[i] = excl;
        if (i == N - 1) rowptr[N] = excl + v;
        __syncthreads();
        if (tid == 1023) carry_s = carry + woff[15] + wsum[15];
        __syncthreads();
    }
}

__global__ void k_initcur(const int* __restrict__ rowptr, int* __restrict__ cur, int N) {
    int i = blockIdx.x * blockDim.x + threadIdx.x;
    if (i < N) cur[i] = rowptr[i];
}

__global__ void k_scatter(const int* __restrict__ src, const int* __restrict__ dst,
                          int* __restrict__ cur, int* __restrict__ perm,
                          int* __restrict__ csr_dst, int E) {
    int e = blockIdx.x * blockDim.x + threadIdx.x;
    if (e >= E) return;
    int pos = atomicAdd(&cur[src[e]], 1);
    perm[pos] = e;
    csr_dst[pos] = dst[e];
}

// ---------------- per-layer kernels ----------------

// thread per undirected edge t: F[t], F[t+EU]; DG atomics
__global__ void k_edgeF(const float2* __restrict__ P, const float2* __restrict__ Q,
                        const int* __restrict__ src, const int* __restrict__ dst,
                        float2* __restrict__ F, float* __restrict__ DG, int EU) {
    int t = blockIdx.x * blockDim.x + threadIdx.x;
    if (t >= EU) return;
    int u = src[t], v = dst[t];
    float2 Pu = P[u], Qv = Q[v], Pv = P[v], Qu = Q[u];
    float2 ff = make_float2(tanhf(Pu.x + Qv.x), tanhf(Pu.y + Qv.y));  // edge t: u->v
    float2 fb = make_float2(tanhf(Pv.x + Qu.x), tanhf(Pv.y + Qu.y));  // edge t+EU: v->u
    F[t] = ff;
    F[t + EU] = fb;
    atomicAdd(&DG[(size_t)u * 2],     ff.x * ff.x);
    atomicAdd(&DG[(size_t)u * 2 + 1], ff.y * ff.y);
    atomicAdd(&DG[(size_t)v * 2],     fb.x * fb.x);
    atomicAdd(&DG[(size_t)v * 2 + 1], fb.y * fb.y);
}

// thread per csr position: csr_w[pos] = -F[e]*F[rev]*rsqrt(DG[src]+1)*rsqrt(DG[dst]+1)
__global__ void k_csrw(const int* __restrict__ perm, const int* __restrict__ csr_dst,
                       const int* __restrict__ src, const float2* __restrict__ F,
                       const float* __restrict__ DG, float2* __restrict__ csr_w, int E) {
    int pos = blockIdx.x * blockDim.x + threadIdx.x;
    if (pos >= E) return;
    int e = perm[pos];
    int EU = E >> 1;
    int r = (e < EU) ? e + EU : e - EU;
    int si = src[e], di = csr_dst[pos];
    float2 f  = F[e];
    float2 fr = F[r];
    float2 gs = *(const float2*)(DG + (size_t)si * 2);
    float2 gd = *(const float2*)(DG + (size_t)di * 2);
    float2 o;
    o.x = -f.x * fr.x * rsqrtf(gs.x + 1.f) * rsqrtf(gd.x + 1.f);
    o.y = -f.y * fr.y * rsqrtf(gs.y + 1.f) * rsqrtf(gd.y + 1.f);
    csr_w[pos] = o;
}

// per node: XW = (Wl ⊗ Wr) X ; writes fp32 + bf16 copies
__global__ void k_lr(const float* __restrict__ X, const float* __restrict__ Wl,
                     const float* __restrict__ Wr, float* __restrict__ XWf,
                     unsigned short* __restrict__ XWh, int N) {
    __shared__ float wrS[H * 33];
    __shared__ float xs[4][DH];
    for (int t = threadIdx.x; t < H * H; t += blockDim.x)
        wrS[(t >> 5) * 33 + (t & 31)] = Wr[t];
    int node0 = blockIdx.x * 4;
    {
        int t = threadIdx.x;
        int nn = t >> 6, cc = t & 63;
        int node = node0 + nn;
        xs[nn][cc] = (node < N) ? X[(size_t)node * DH + cc] : 0.f;
    }
    __syncthreads();
    int nn = threadIdx.x >> 6;
    int node = node0 + nn;
    if (node >= N) return;
    int sc = threadIdx.x & 63;
    int sp = sc >> 5;
    int c  = sc & 31;
    float wl0 = Wl[sp * 2 + 0], wl1 = Wl[sp * 2 + 1];
    float acc = 0.f;
    #pragma unroll
    for (int cp = 0; cp < H; ++cp) {
        float mixed = wl0 * xs[nn][cp] + wl1 * xs[nn][32 + cp];
        acc += mixed * wrS[c * 33 + cp];
    }
    size_t idx = (size_t)node * DH + sp * 32 + c;
    XWf[idx] = acc;
    XWh[idx] = f2bf(acc);
}

// wave per node: y = diagw*XWf[i] + sum csr_w*XWh[csr_dst]; X = coeff*X - elu(y); fused next-layer P/Q
__global__ void k_spmm_fin_pq(const float* __restrict__ XWf, const unsigned short* __restrict__ XWh,
                              const float2* __restrict__ csr_w, const int* __restrict__ rowptr,
                              const int* __restrict__ csr_dst, const float* __restrict__ DG,
                              const float* __restrict__ eps_l, const float* __restrict__ Wsn,
                              float* __restrict__ X, float2* __restrict__ P,
                              float2* __restrict__ Q, int N) {
    int wid = (blockIdx.x * blockDim.x + threadIdx.x) >> 6;
    int lane = threadIdx.x & 63;
    if (wid >= N) return;
    int s = lane >> 5;
    float dg = DG[(size_t)wid * 2 + s];
    float acc = dg / (dg + 1.f) * XWf[(size_t)wid * DH + lane];
    int pos = rowptr[wid], end = rowptr[wid + 1];
    float accA = 0.f, accB = 0.f;
    int n4 = pos + ((end - pos) & ~3);
    for (; pos < n4; pos += 4) {
        int d0 = csr_dst[pos], d1 = csr_dst[pos + 1];
        int d2 = csr_dst[pos + 2], d3 = csr_dst[pos + 3];
        float2 w01 = csr_w[pos],     w11 = csr_w[pos + 1];
        float2 w21 = csr_w[pos + 2], w31 = csr_w[pos + 3];
        float w0 = s ? w01.y : w01.x;
        float w1 = s ? w11.y : w11.x;
        float w2 = s ? w21.y : w21.x;
        float w3 = s ? w31.y : w31.x;
        float g0 = bf2f(XWh[(size_t)d0 * DH + lane]);
        float g1 = bf2f(XWh[(size_t)d1 * DH + lane]);
        float g2 = bf2f(XWh[(size_t)d2 * DH + lane]);
        float g3 = bf2f(XWh[(size_t)d3 * DH + lane]);
        accA += w0 * g0; accB += w1 * g1;
        accA += w2 * g2; accB += w3 * g3;
    }
    for (; pos < end; ++pos) {
        float2 wv = csr_w[pos];
        accA += (s ? wv.y : wv.x) * bf2f(XWh[(size_t)csr_dst[pos] * DH + lane]);
    }
    acc += accA + accB;
    float coeff = 1.f + tanhf(eps_l[s]);
    size_t idx = (size_t)wid * DH + lane;
    float xnew = coeff * X[idx] - eluf(acc);
    X[idx] = xnew;
    if (Wsn) {
        float p0 = xnew * Wsn[lane], q0 = xnew * Wsn[64 + lane];
        float p1 = xnew * Wsn[128 + lane], q1 = xnew * Wsn[192 + lane];
        #pragma unroll
        for (int ofs = 32; ofs; ofs >>= 1) {
            p0 += __shfl_xor(p0, ofs); q0 += __shfl_xor(q0, ofs);
            p1 += __shfl_xor(p1, ofs); q1 += __shfl_xor(q1, ofs);
        }
        if (lane == 0) { P[wid] = make_float2(p0, p1); Q[wid] = make_float2(q0, q1); }
    }
}

// out = X @ W2^T + b2 ; [N,32]
__global__ void k_out(const float* __restrict__ X, const float* __restrict__ W2,
                      const float* __restrict__ b2, float* __restrict__ out, int N) {
    __shared__ float w2S[OUTC * 65];
    __shared__ float xs[8][DH];
    for (int t = threadIdx.x; t < OUTC * DH; t += blockDim.x)
        w2S[(t >> 6) * 65 + (t & 63)] = W2[t];
    int node0 = blockIdx.x * 8;
    for (int t = threadIdx.x; t < 8 * DH; t += blockDim.x) {
        int nn = t >> 6, k = t & 63;
        int node = node0 + nn;
        xs[nn][k] = (node < N) ? X[(size_t)node * DH + k] : 0.f;
    }
    __syncthreads();
    int nn = threadIdx.x >> 5;
    int oc = threadIdx.x & 31;
    int node = node0 + nn;
    if (node >= N) return;
    float acc = b2[oc];
    #pragma unroll
    for (int k = 0; k < DH; ++k) acc += xs[nn][k] * w2S[oc * 65 + k];
    out[(size_t)node * OUTC + oc] = acc;
}

extern "C" void kernel_launch(void* const* d_in, const int* in_sizes, int n_in,
                              void* d_out, int out_size, void* d_ws, size_t ws_size,
                              hipStream_t stream) {
    const float* xin    = (const float*)d_in[0];
    const int*   ei     = (const int*)d_in[1];
    const float* W1     = (const float*)d_in[2];
    const float* b1     = (const float*)d_in[3];
    const float* Wsheaf = (const float*)d_in[4];
    const float* Wleft  = (const float*)d_in[5];
    const float* Wright = (const float*)d_in[6];
    const float* eps    = (const float*)d_in[7];
    const float* W2     = (const float*)d_in[8];
    const float* b2     = (const float*)d_in[9];
    float* out = (float*)d_out;

    int N = in_sizes[0] / INCH;
    int E = in_sizes[1] / 2;
    int EU = E / 2;
    const int* src = ei;
    const int* dst = ei + E;

    size_t off = 0;
    auto alloc = [&](size_t nbytes) {
        char* p = (char*)d_ws + off;
        off += (nbytes + 255) & ~(size_t)255;
        return p;
    };
    float*          X       = (float*)alloc((size_t)N * DH * 4);
    float*          XWf     = (float*)alloc((size_t)N * DH * 4);
    unsigned short* XWh     = (unsigned short*)alloc((size_t)N * DH * 2);
    float2*         F       = (float2*)alloc((size_t)E * 8);
    float2*         csr_w   = (float2*)alloc((size_t)E * 8);
    float*          DG      = (float*)alloc((size_t)N * 2 * 4);
    float2*         P       = (float2*)alloc((size_t)N * 8);
    float2*         Q       = (float2*)alloc((size_t)N * 8);
    int*            deg     = (int*)alloc((size_t)N * 4);
    int*            rowptr  = (int*)alloc(((size_t)N + 1) * 4);
    int*            cur     = (int*)alloc((size_t)N * 4);
    int*            perm    = (int*)alloc((size_t)E * 4);
    int*            csr_dst = (int*)alloc((size_t)E * 4);

    // ---- CSR by src (once per call) ----
    hipMemsetAsync(deg, 0, (size_t)N * sizeof(int), stream);
    k_hist<<<(E + 255) / 256, 256, 0, stream>>>(src, deg, E);
    k_scan<<<1, 1024, 0, stream>>>(deg, rowptr, N);
    k_initcur<<<(N + 255) / 256, 256, 0, stream>>>(rowptr, cur, N);
    k_scatter<<<(E + 255) / 256, 256, 0, stream>>>(src, dst, cur, perm, csr_dst, E);

    k_mlp1_pq<<<(N + 3) / 4, 256, 0, stream>>>(xin, W1, b1, Wsheaf, X, P, Q, N);

    for (int l = 0; l < LAYERS; ++l) {
        hipMemsetAsync(DG, 0, (size_t)N * 2 * sizeof(float), stream);
        k_edgeF<<<(EU + 255) / 256, 256, 0, stream>>>(P, Q, src, dst, F, DG, EU);
        k_csrw<<<(E + 255) / 256, 256, 0, stream>>>(perm, csr_dst, src, F, DG, csr_w, E);
        k_lr<<<(N + 3) / 4, 256, 0, stream>>>(X, Wleft + l * 4, Wright + l * H * H, XWf, XWh, N);
        const float* Wsn = (l + 1 < LAYERS) ? (Wsheaf + (l + 1) * 2 * INCH) : nullptr;
        k_spmm_fin_pq<<<(N + 3) / 4, 256, 0, stream>>>(XWf, XWh, csr_w, rowptr, csr_dst,
                                                       DG, eps + l * 2, Wsn, X, P, Q, N);
    }

    k_out<<<(N + 7) / 8, 256, 0, stream>>>(X, W2, b2, out, N);
}

// Round 4
// 797.481 us; speedup vs baseline: 2.0479x; 1.2451x over previous
//
#include <hip/hip_runtime.h>
#include <math.h>

#define INCH 128
#define DH 64     // d*h
#define H  32
#define D  2
#define LAYERS 4
#define OUTC 32

typedef __fp16 half4 __attribute__((ext_vector_type(4)));
typedef float  f32x4 __attribute__((ext_vector_type(4)));

__device__ __forceinline__ float eluf(float v) { return v > 0.f ? v : expm1f(v); }

// ---------------- one-time prep: f16 copies of W1, W2, kron(Wl,Wr) ----------------
__global__ void k_prep(const float* __restrict__ W1, const float* __restrict__ W2,
                       const float* __restrict__ Wleft, const float* __restrict__ Wright,
                       __fp16* __restrict__ W1h, __fp16* __restrict__ W2h,
                       __fp16* __restrict__ Mlrh) {
    int idx = blockIdx.x * blockDim.x + threadIdx.x;
    if (idx < DH * INCH) {
        W1h[idx] = (__fp16)W1[idx];
    } else if (idx < DH * INCH + OUTC * DH) {
        int i = idx - DH * INCH;
        W2h[i] = (__fp16)W2[i];
    } else if (idx < DH * INCH + OUTC * DH + LAYERS * DH * DH) {
        int i = idx - DH * INCH - OUTC * DH;
        int l = i >> 12;          // 4096 per layer
        int r = i & 4095;
        int row = r >> 6;         // sp*32 + c
        int col = r & 63;         // s*32 + cp
        int sp = row >> 5, c = row & 31;
        int s  = col >> 5, cp = col & 31;
        Mlrh[i] = (__fp16)(Wleft[l * 4 + sp * 2 + s] * Wright[l * 1024 + c * 32 + cp]);
    }
}

// ---------------- CSR build (by src) ----------------
__global__ void k_hist(const int* __restrict__ src, int* __restrict__ deg, int E) {
    int e = blockIdx.x * blockDim.x + threadIdx.x;
    if (e < E) atomicAdd(&deg[src[e]], 1);
}

__global__ void k_scan(const int* __restrict__ deg, int* __restrict__ rowptr, int N) {
    __shared__ int wsum[16];
    __shared__ int woff[16];
    __shared__ int carry_s;
    int tid = threadIdx.x;
    int lane = tid & 63, wid = tid >> 6;
    if (tid == 0) carry_s = 0;
    __syncthreads();
    for (int base = 0; base < N; base += 1024) {
        int i = base + tid;
        int v = (i < N) ? deg[i] : 0;
        int incl = v;
        #pragma unroll
        for (int ofs = 1; ofs < 64; ofs <<= 1) {
            int t = __shfl_up(incl, ofs);
            if (lane >= ofs) incl += t;
        }
        if (lane == 63) wsum[wid] = incl;
        __syncthreads();
        if (wid == 0 && lane < 16) {
            int w = wsum[lane];
            int wi = w;
            #pragma unroll
            for (int ofs = 1; ofs < 16; ofs <<= 1) {
                int t = __shfl_up(wi, ofs);
                if (lane >= ofs) wi += t;
            }
            woff[lane] = wi - w;
        }
        __syncthreads();
        int carry = carry_s;
        int excl = carry + woff[wid] + incl - v;
        if (i < N) rowptr[i] = excl;
        if (i == N - 1) rowptr[N] = excl + v;
        __syncthreads();
        if (tid == 1023) carry_s = carry + woff[15] + wsum[15];
        __syncthreads();
    }
}

__global__ void k_initcur(const int* __restrict__ rowptr, int* __restrict__ cur, int N) {
    int i = blockIdx.x * blockDim.x + threadIdx.x;
    if (i < N) cur[i] = rowptr[i];
}

__global__ void k_scatter(const int* __restrict__ src, const int* __restrict__ dst,
                          int* __restrict__ cur, int* __restrict__ iperm,
                          int* __restrict__ csr_dst, int E) {
    int e = blockIdx.x * blockDim.x + threadIdx.x;
    if (e >= E) return;
    int pos = atomicAdd(&cur[src[e]], 1);
    csr_dst[pos] = dst[e];
    iperm[e] = pos;
}

// ---------------- MFMA GEMM kernels (16x16x16 f16) ----------------

// X = elu(xin @ W1^T + b1); 16 nodes/block, 4 waves each handle 16 oc
__global__ __launch_bounds__(256) void k_mlp1(const float* __restrict__ xin,
                                              const __fp16* __restrict__ W1h,
                                              const float* __restrict__ b1,
                                              float* __restrict__ X, int N) {
    __shared__ float xs[16 * INCH];          // 8 KB
    __shared__ __fp16 wsh[DH * 132];         // padded, ~16.9 KB
    int t = threadIdx.x;
    int node0 = blockIdx.x * 16;
    // stage x (coalesced float4)
    for (int i = t; i < 16 * INCH / 4; i += 256) {
        int r = i >> 5, c = (i & 31) * 4;
        int node = node0 + r;
        float4 v = (node < N) ? *(const float4*)(xin + (size_t)node * INCH + c)
                              : make_float4(0.f, 0.f, 0.f, 0.f);
        *(float4*)&xs[r * INCH + c] = v;
    }
    // stage W1h
    for (int i = t; i < DH * INCH / 4; i += 256) {
        int r = i >> 5, c = (i & 31) * 4;
        *(uint2*)&wsh[r * 132 + c] = ((const uint2*)W1h)[i];
    }
    __syncthreads();
    int w = t >> 6, lane = t & 63;
    int oc0 = w * 16;
    int rr = lane & 15, g = lane >> 4;
    f32x4 acc = {0.f, 0.f, 0.f, 0.f};
    #pragma unroll
    for (int ks = 0; ks < INCH / 16; ++ks) {
        float4 xv = *(const float4*)&xs[rr * INCH + ks * 16 + g * 4];
        half4 af = {(__fp16)xv.x, (__fp16)xv.y, (__fp16)xv.z, (__fp16)xv.w};
        half4 bf = *(const half4*)&wsh[(oc0 + rr) * 132 + ks * 16 + g * 4];
        acc = __builtin_amdgcn_mfma_f32_16x16x16f16(af, bf, acc, 0, 0, 0);
    }
    int oc = oc0 + rr;
    float bb = b1[oc];
    #pragma unroll
    for (int r = 0; r < 4; ++r) {
        int node = node0 + g * 4 + r;
        if (node < N) X[(size_t)node * DH + oc] = eluf(acc[r] + bb);
    }
}

// wave per node: P/Q for layer 0
__global__ void k_pq(const float* __restrict__ X, const float* __restrict__ Wsl,
                     float2* __restrict__ P, float2* __restrict__ Q, int N) {
    int wid = (blockIdx.x * blockDim.x + threadIdx.x) >> 6;
    int lane = threadIdx.x & 63;
    if (wid >= N) return;
    float x = X[(size_t)wid * DH + lane];
    float p0 = x * Wsl[lane];
    float q0 = x * Wsl[64 + lane];
    float p1 = x * Wsl[128 + lane];
    float q1 = x * Wsl[192 + lane];
    #pragma unroll
    for (int ofs = 32; ofs; ofs >>= 1) {
        p0 += __shfl_xor(p0, ofs);
        q0 += __shfl_xor(q0, ofs);
        p1 += __shfl_xor(p1, ofs);
        q1 += __shfl_xor(q1, ofs);
    }
    if (lane == 0) {
        P[wid] = make_float2(p0, p1);
        Q[wid] = make_float2(q0, q1);
    }
}

// XW = X @ kron(Wl,Wr)^T ; writes fp32 + f16 copies
__global__ __launch_bounds__(256) void k_lr(const float* __restrict__ X,
                                            const __fp16* __restrict__ Mlrh_l,
                                            float* __restrict__ XWf,
                                            __fp16* __restrict__ XWh, int N) {
    __shared__ float xs[16 * DH];            // 4 KB
    __shared__ __fp16 mlh[DH * 68];          // ~8.7 KB
    int t = threadIdx.x;
    int node0 = blockIdx.x * 16;
    for (int i = t; i < 16 * DH / 4; i += 256) {
        int r = i >> 4, c = (i & 15) * 4;
        int node = node0 + r;
        float4 v = (node < N) ? *(const float4*)(X + (size_t)node * DH + c)
                              : make_float4(0.f, 0.f, 0.f, 0.f);
        *(float4*)&xs[r * DH + c] = v;
    }
    for (int i = t; i < DH * DH / 4; i += 256) {
        int r = i >> 4, c = (i & 15) * 4;
        *(uint2*)&mlh[r * 68 + c] = ((const uint2*)Mlrh_l)[i];
    }
    __syncthreads();
    int w = t >> 6, lane = t & 63;
    int oc0 = w * 16;
    int rr = lane & 15, g = lane >> 4;
    f32x4 acc = {0.f, 0.f, 0.f, 0.f};
    #pragma unroll
    for (int ks = 0; ks < DH / 16; ++ks) {
        float4 xv = *(const float4*)&xs[rr * DH + ks * 16 + g * 4];
        half4 af = {(__fp16)xv.x, (__fp16)xv.y, (__fp16)xv.z, (__fp16)xv.w};
        half4 bf = *(const half4*)&mlh[(oc0 + rr) * 68 + ks * 16 + g * 4];
        acc = __builtin_amdgcn_mfma_f32_16x16x16f16(af, bf, acc, 0, 0, 0);
    }
    int oc = oc0 + rr;
    #pragma unroll
    for (int r = 0; r < 4; ++r) {
        int node = node0 + g * 4 + r;
        if (node < N) {
            size_t idx = (size_t)node * DH + oc;
            XWf[idx] = acc[r];
            XWh[idx] = (__fp16)acc[r];
        }
    }
}

// out = X @ W2^T + b2 ; 32 nodes/block
__global__ __launch_bounds__(256) void k_out(const float* __restrict__ X,
                                             const __fp16* __restrict__ W2h,
                                             const float* __restrict__ b2,
                                             float* __restrict__ out, int N) {
    __shared__ float xs[32 * DH];            // 8 KB
    __shared__ __fp16 w2s[OUTC * 68];        // ~4.3 KB
    int t = threadIdx.x;
    int node0 = blockIdx.x * 32;
    for (int i = t; i < 32 * DH / 4; i += 256) {
        int r = i >> 4, c = (i & 15) * 4;
        int node = node0 + r;
        float4 v = (node < N) ? *(const float4*)(X + (size_t)node * DH + c)
                              : make_float4(0.f, 0.f, 0.f, 0.f);
        *(float4*)&xs[r * DH + c] = v;
    }
    for (int i = t; i < OUTC * DH / 4; i += 256) {
        int r = i >> 4, c = (i & 15) * 4;
        *(uint2*)&w2s[r * 68 + c] = ((const uint2*)W2h)[i];
    }
    __syncthreads();
    int w = t >> 6, lane = t & 63;
    int nt = w >> 1;
    int oc0 = (w & 1) * 16;
    int rr = lane & 15, g = lane >> 4;
    f32x4 acc = {0.f, 0.f, 0.f, 0.f};
    #pragma unroll
    for (int ks = 0; ks < DH / 16; ++ks) {
        float4 xv = *(const float4*)&xs[(nt * 16 + rr) * DH + ks * 16 + g * 4];
        half4 af = {(__fp16)xv.x, (__fp16)xv.y, (__fp16)xv.z, (__fp16)xv.w};
        half4 bf = *(const half4*)&w2s[(oc0 + rr) * 68 + ks * 16 + g * 4];
        acc = __builtin_amdgcn_mfma_f32_16x16x16f16(af, bf, acc, 0, 0, 0);
    }
    int oc = oc0 + rr;
    float bb = b2[oc];
    #pragma unroll
    for (int r = 0; r < 4; ++r) {
        int node = node0 + nt * 16 + g * 4 + r;
        if (node < N) out[(size_t)node * OUTC + oc] = acc[r] + bb;
    }
}

// ---------------- per-layer edge kernels ----------------

// thread per undirected edge: prodF = F_fwd*F_bwd; DG atomics
__global__ void k_edgeF(const float2* __restrict__ P, const float2* __restrict__ Q,
                        const int* __restrict__ src, const int* __restrict__ dst,
                        float2* __restrict__ prodF, float* __restrict__ DG, int EU) {
    int t = blockIdx.x * blockDim.x + threadIdx.x;
    if (t >= EU) return;
    int u = src[t], v = dst[t];
    float2 Pu = P[u], Qv = Q[v], Pv = P[v], Qu = Q[u];
    float ffx = tanhf(Pu.x + Qv.x), ffy = tanhf(Pu.y + Qv.y);
    float fbx = tanhf(Pv.x + Qu.x), fby = tanhf(Pv.y + Qu.y);
    prodF[t] = make_float2(ffx * fbx, ffy * fby);
    atomicAdd(&DG[(size_t)u * 2],     ffx * ffx);
    atomicAdd(&DG[(size_t)u * 2 + 1], ffy * ffy);
    atomicAdd(&DG[(size_t)v * 2],     fbx * fbx);
    atomicAdd(&DG[(size_t)v * 2 + 1], fby * fby);
}

// thread per undirected edge: w = -prodF*dinv_u*dinv_v, scatter to both CSR slots
__global__ void k_csrw(const int* __restrict__ src, const int* __restrict__ dst,
                       const float2* __restrict__ prodF, const float* __restrict__ DG,
                       const int* __restrict__ iperm, float2* __restrict__ csr_w, int EU) {
    int t = blockIdx.x * blockDim.x + threadIdx.x;
    if (t >= EU) return;
    int u = src[t], v = dst[t];
    float2 pf = prodF[t];
    float2 gu = *(const float2*)(DG + (size_t)u * 2);
    float2 gv = *(const float2*)(DG + (size_t)v * 2);
    float2 w;
    w.x = -pf.x * rsqrtf(gu.x + 1.f) * rsqrtf(gv.x + 1.f);
    w.y = -pf.y * rsqrtf(gu.y + 1.f) * rsqrtf(gv.y + 1.f);
    csr_w[iperm[t]] = w;
    csr_w[iperm[t + EU]] = w;
}

// wave per node, 4 edges/iter, half4 gathers; fused elu/residual + next-layer P/Q
__global__ void k_spmm_fin_pq(const float* __restrict__ XWf, const __fp16* __restrict__ XWh,
                              const float2* __restrict__ csr_w, const int* __restrict__ rowptr,
                              const int* __restrict__ csr_dst, const float* __restrict__ DG,
                              const float* __restrict__ eps_l, const float* __restrict__ Wsn,
                              float* __restrict__ X, float2* __restrict__ P,
                              float2* __restrict__ Q, int N) {
    int wid = (blockIdx.x * blockDim.x + threadIdx.x) >> 6;
    int lane = threadIdx.x & 63;
    if (wid >= N) return;
    int q = lane >> 4;        // edge slot 0..3
    int m = lane & 15;        // channel quad: channels 4m..4m+3
    int s = m >> 3;           // stalk of these channels
    int pos = rowptr[wid], end = rowptr[wid + 1];
    float ax = 0.f, ay = 0.f, az = 0.f, aw = 0.f;
    #pragma unroll 2
    for (int base = pos; base < end; base += 4) {
        int idx = base + q;
        bool valid = idx < end;
        int d = 0;
        float wgt = 0.f;
        if (valid) {
            d = csr_dst[idx];
            float2 wv = csr_w[idx];
            wgt = s ? wv.y : wv.x;
        }
        half4 g = *(const half4*)(XWh + (size_t)d * DH + m * 4);
        ax += wgt * (float)g.x;
        ay += wgt * (float)g.y;
        az += wgt * (float)g.z;
        aw += wgt * (float)g.w;
    }
    // reduce across the 4 edge slots (lanes m, m+16, m+32, m+48)
    ax += __shfl_xor(ax, 16); ay += __shfl_xor(ay, 16);
    az += __shfl_xor(az, 16); aw += __shfl_xor(aw, 16);
    ax += __shfl_xor(ax, 32); ay += __shfl_xor(ay, 32);
    az += __shfl_xor(az, 32); aw += __shfl_xor(aw, 32);
    if (q == 0) {
        float dg = DG[(size_t)wid * 2 + s];
        float diag = dg / (dg + 1.f);
        size_t base_idx = (size_t)wid * DH + m * 4;
        float4 xwf = *(const float4*)(XWf + base_idx);
        float4 y;
        y.x = diag * xwf.x + ax;
        y.y = diag * xwf.y + ay;
        y.z = diag * xwf.z + az;
        y.w = diag * xwf.w + aw;
        float coeff = 1.f + tanhf(eps_l[s]);
        float4 xold = *(const float4*)(X + base_idx);
        float4 xn;
        xn.x = coeff * xold.x - eluf(y.x);
        xn.y = coeff * xold.y - eluf(y.y);
        xn.z = coeff * xold.z - eluf(y.z);
        xn.w = coeff * xold.w - eluf(y.w);
        *(float4*)(X + base_idx) = xn;
        if (Wsn) {
            float4 wa = *(const float4*)(Wsn + m * 4);
            float4 wb = *(const float4*)(Wsn + 64 + m * 4);
            float4 wc = *(const float4*)(Wsn + 128 + m * 4);
            float4 wd = *(const float4*)(Wsn + 192 + m * 4);
            float p0 = xn.x * wa.x + xn.y * wa.y + xn.z * wa.z + xn.w * wa.w;
            float q0 = xn.x * wb.x + xn.y * wb.y + xn.z * wb.z + xn.w * wb.w;
            float p1 = xn.x * wc.x + xn.y * wc.y + xn.z * wc.z + xn.w * wc.w;
            float q1 = xn.x * wd.x + xn.y * wd.y + xn.z * wd.z + xn.w * wd.w;
            #pragma unroll
            for (int ofs = 8; ofs; ofs >>= 1) {
                p0 += __shfl_xor(p0, ofs);
                q0 += __shfl_xor(q0, ofs);
                p1 += __shfl_xor(p1, ofs);
                q1 += __shfl_xor(q1, ofs);
            }
            if (m == 0) {
                P[wid] = make_float2(p0, p1);
                Q[wid] = make_float2(q0, q1);
            }
        }
    }
}

extern "C" void kernel_launch(void* const* d_in, const int* in_sizes, int n_in,
                              void* d_out, int out_size, void* d_ws, size_t ws_size,
                              hipStream_t stream) {
    const float* xin    = (const float*)d_in[0];
    const int*   ei     = (const int*)d_in[1];
    const float* W1     = (const float*)d_in[2];
    const float* b1     = (const float*)d_in[3];
    const float* Wsheaf = (const float*)d_in[4];
    const float* Wleft  = (const float*)d_in[5];
    const float* Wright = (const float*)d_in[6];
    const float* eps    = (const float*)d_in[7];
    const float* W2     = (const float*)d_in[8];
    const float* b2     = (const float*)d_in[9];
    float* out = (float*)d_out;

    int N = in_sizes[0] / INCH;
    int E = in_sizes[1] / 2;
    int EU = E / 2;
    const int* src = ei;
    const int* dst = ei + E;

    size_t off = 0;
    auto alloc = [&](size_t nbytes) {
        char* p = (char*)d_ws + off;
        off += (nbytes + 255) & ~(size_t)255;
        return p;
    };
    float*   X       = (float*)alloc((size_t)N * DH * 4);
    float*   XWf     = (float*)alloc((size_t)N * DH * 4);
    __fp16*  XWh     = (__fp16*)alloc((size_t)N * DH * 2);
    float2*  prodF   = (float2*)alloc((size_t)EU * 8);
    float2*  csr_w   = (float2*)alloc((size_t)E * 8);
    float*   DG      = (float*)alloc((size_t)N * 2 * 4);
    float2*  P       = (float2*)alloc((size_t)N * 8);
    float2*  Q       = (float2*)alloc((size_t)N * 8);
    int*     deg     = (int*)alloc((size_t)N * 4);
    int*     rowptr  = (int*)alloc(((size_t)N + 1) * 4);
    int*     cur     = (int*)alloc((size_t)N * 4);
    int*     iperm   = (int*)alloc((size_t)E * 4);
    int*     csr_dst = (int*)alloc((size_t)E * 4);
    __fp16*  W1h     = (__fp16*)alloc((size_t)DH * INCH * 2);
    __fp16*  W2h     = (__fp16*)alloc((size_t)OUTC * DH * 2);
    __fp16*  Mlrh    = (__fp16*)alloc((size_t)LAYERS * DH * DH * 2);

    // one-time prep + CSR build
    int prep_total = DH * INCH + OUTC * DH + LAYERS * DH * DH;
    k_prep<<<(prep_total + 255) / 256, 256, 0, stream>>>(W1, W2, Wleft, Wright, W1h, W2h, Mlrh);
    hipMemsetAsync(deg, 0, (size_t)N * sizeof(int), stream);
    k_hist<<<(E + 255) / 256, 256, 0, stream>>>(src, deg, E);
    k_scan<<<1, 1024, 0, stream>>>(deg, rowptr, N);
    k_initcur<<<(N + 255) / 256, 256, 0, stream>>>(rowptr, cur, N);
    k_scatter<<<(E + 255) / 256, 256, 0, stream>>>(src, dst, cur, iperm, csr_dst, E);

    k_mlp1<<<(N + 15) / 16, 256, 0, stream>>>(xin, W1h, b1, X, N);
    k_pq<<<(N + 3) / 4, 256, 0, stream>>>(X, Wsheaf, P, Q, N);

    for (int l = 0; l < LAYERS; ++l) {
        hipMemsetAsync(DG, 0, (size_t)N * 2 * sizeof(float), stream);
        k_edgeF<<<(EU + 255) / 256, 256, 0, stream>>>(P, Q, src, dst, prodF, DG, EU);
        k_csrw<<<(EU + 255) / 256, 256, 0, stream>>>(src, dst, prodF, DG, iperm, csr_w, EU);
        k_lr<<<(N + 15) / 16, 256, 0, stream>>>(X, Mlrh + (size_t)l * DH * DH, XWf, XWh, N);
        const float* Wsn = (l + 1 < LAYERS) ? (Wsheaf + (l + 1) * 2 * INCH) : nullptr;
        k_spmm_fin_pq<<<(N + 3) / 4, 256, 0, stream>>>(XWf, XWh, csr_w, rowptr, csr_dst,
                                                       DG, eps + l * 2, Wsn, X, P, Q, N);
    }

    k_out<<<(N + 31) / 32, 256, 0, stream>>>(X, W2h, b2, out, N);
}

// Round 5
// 501.768 us; speedup vs baseline: 3.2549x; 1.5893x over previous
//
#include <hip/hip_runtime.h>
#include <math.h>

#define INCH 128
#define DH 64     // d*h
#define H  32
#define D  2
#define LAYERS 4
#define OUTC 32

typedef __fp16 half4 __attribute__((ext_vector_type(4)));
typedef float  f32x4 __attribute__((ext_vector_type(4)));

__device__ __forceinline__ float eluf(float v) { return v > 0.f ? v : expm1f(v); }

// ---------------- one-time prep: f16 copies of W1, W2, kron(Wl,Wr) ----------------
__global__ void k_prep(const float* __restrict__ W1, const float* __restrict__ W2,
                       const float* __restrict__ Wleft, const float* __restrict__ Wright,
                       __fp16* __restrict__ W1h, __fp16* __restrict__ W2h,
                       __fp16* __restrict__ Mlrh) {
    int idx = blockIdx.x * blockDim.x + threadIdx.x;
    if (idx < DH * INCH) {
        W1h[idx] = (__fp16)W1[idx];
    } else if (idx < DH * INCH + OUTC * DH) {
        int i = idx - DH * INCH;
        W2h[i] = (__fp16)W2[i];
    } else if (idx < DH * INCH + OUTC * DH + LAYERS * DH * DH) {
        int i = idx - DH * INCH - OUTC * DH;
        int l = i >> 12;
        int r = i & 4095;
        int row = r >> 6;         // sp*32 + c
        int col = r & 63;         // s*32 + cp
        int sp = row >> 5, c = row & 31;
        int s  = col >> 5, cp = col & 31;
        Mlrh[i] = (__fp16)(Wleft[l * 4 + sp * 2 + s] * Wright[l * 1024 + c * 32 + cp]);
    }
}

// ---------------- CSR build (by src) ----------------
__global__ void k_hist(const int* __restrict__ src, int* __restrict__ deg, int E) {
    int e = blockIdx.x * blockDim.x + threadIdx.x;
    if (e < E) atomicAdd(&deg[src[e]], 1);
}

__global__ void k_scan(const int* __restrict__ deg, int* __restrict__ rowptr, int N) {
    __shared__ int wsum[16];
    __shared__ int woff[16];
    __shared__ int carry_s;
    int tid = threadIdx.x;
    int lane = tid & 63, wid = tid >> 6;
    if (tid == 0) carry_s = 0;
    __syncthreads();
    for (int base = 0; base < N; base += 1024) {
        int i = base + tid;
        int v = (i < N) ? deg[i] : 0;
        int incl = v;
        #pragma unroll
        for (int ofs = 1; ofs < 64; ofs <<= 1) {
            int t = __shfl_up(incl, ofs);
            if (lane >= ofs) incl += t;
        }
        if (lane == 63) wsum[wid] = incl;
        __syncthreads();
        if (wid == 0 && lane < 16) {
            int w = wsum[lane];
            int wi = w;
            #pragma unroll
            for (int ofs = 1; ofs < 16; ofs <<= 1) {
                int t = __shfl_up(wi, ofs);
                if (lane >= ofs) wi += t;
            }
            woff[lane] = wi - w;
        }
        __syncthreads();
        int carry = carry_s;
        int excl = carry + woff[wid] + incl - v;
        if (i < N) rowptr[i] = excl;
        if (i == N - 1) rowptr[N] = excl + v;
        __syncthreads();
        if (tid == 1023) carry_s = carry + woff[15] + wsum[15];
        __syncthreads();
    }
}

__global__ void k_initcur(const int* __restrict__ rowptr, int* __restrict__ cur, int N) {
    int i = blockIdx.x * blockDim.x + threadIdx.x;
    if (i < N) cur[i] = rowptr[i];
}

// csr_dst[pos] = dst[e]; csr_eu[pos] = undirected edge id of e
__global__ void k_scatter(const int* __restrict__ src, const int* __restrict__ dst,
                          int* __restrict__ cur, int* __restrict__ csr_dst,
                          int* __restrict__ csr_eu, int E) {
    int e = blockIdx.x * blockDim.x + threadIdx.x;
    if (e >= E) return;
    int pos = atomicAdd(&cur[src[e]], 1);
    int EU = E >> 1;
    csr_dst[pos] = dst[e];
    csr_eu[pos] = (e < EU) ? e : e - EU;
}

// ---------------- MFMA GEMM kernels (16x16x16 f16) ----------------

__global__ __launch_bounds__(256) void k_mlp1(const float* __restrict__ xin,
                                              const __fp16* __restrict__ W1h,
                                              const float* __restrict__ b1,
                                              float* __restrict__ X, int N) {
    __shared__ float xs[16 * INCH];
    __shared__ __fp16 wsh[DH * 132];
    int t = threadIdx.x;
    int node0 = blockIdx.x * 16;
    for (int i = t; i < 16 * INCH / 4; i += 256) {
        int r = i >> 5, c = (i & 31) * 4;
        int node = node0 + r;
        float4 v = (node < N) ? *(const float4*)(xin + (size_t)node * INCH + c)
                              : make_float4(0.f, 0.f, 0.f, 0.f);
        *(float4*)&xs[r * INCH + c] = v;
    }
    for (int i = t; i < DH * INCH / 4; i += 256) {
        int r = i >> 5, c = (i & 31) * 4;
        *(uint2*)&wsh[r * 132 + c] = ((const uint2*)W1h)[i];
    }
    __syncthreads();
    int w = t >> 6, lane = t & 63;
    int oc0 = w * 16;
    int rr = lane & 15, g = lane >> 4;
    f32x4 acc = {0.f, 0.f, 0.f, 0.f};
    #pragma unroll
    for (int ks = 0; ks < INCH / 16; ++ks) {
        float4 xv = *(const float4*)&xs[rr * INCH + ks * 16 + g * 4];
        half4 af = {(__fp16)xv.x, (__fp16)xv.y, (__fp16)xv.z, (__fp16)xv.w};
        half4 bf = *(const half4*)&wsh[(oc0 + rr) * 132 + ks * 16 + g * 4];
        acc = __builtin_amdgcn_mfma_f32_16x16x16f16(af, bf, acc, 0, 0, 0);
    }
    int oc = oc0 + rr;
    float bb = b1[oc];
    #pragma unroll
    for (int r = 0; r < 4; ++r) {
        int node = node0 + g * 4 + r;
        if (node < N) X[(size_t)node * DH + oc] = eluf(acc[r] + bb);
    }
}

// wave per node: P/Q for layer 0
__global__ void k_pq(const float* __restrict__ X, const float* __restrict__ Wsl,
                     float2* __restrict__ P, float2* __restrict__ Q, int N) {
    int wid = (blockIdx.x * blockDim.x + threadIdx.x) >> 6;
    int lane = threadIdx.x & 63;
    if (wid >= N) return;
    float x = X[(size_t)wid * DH + lane];
    float p0 = x * Wsl[lane];
    float q0 = x * Wsl[64 + lane];
    float p1 = x * Wsl[128 + lane];
    float q1 = x * Wsl[192 + lane];
    #pragma unroll
    for (int ofs = 32; ofs; ofs >>= 1) {
        p0 += __shfl_xor(p0, ofs);
        q0 += __shfl_xor(q0, ofs);
        p1 += __shfl_xor(p1, ofs);
        q1 += __shfl_xor(q1, ofs);
    }
    if (lane == 0) {
        P[wid] = make_float2(p0, p1);
        Q[wid] = make_float2(q0, q1);
    }
}

__global__ __launch_bounds__(256) void k_lr(const float* __restrict__ X,
                                            const __fp16* __restrict__ Mlrh_l,
                                            float* __restrict__ XWf,
                                            __fp16* __restrict__ XWh, int N) {
    __shared__ float xs[16 * DH];
    __shared__ __fp16 mlh[DH * 68];
    int t = threadIdx.x;
    int node0 = blockIdx.x * 16;
    for (int i = t; i < 16 * DH / 4; i += 256) {
        int r = i >> 4, c = (i & 15) * 4;
        int node = node0 + r;
        float4 v = (node < N) ? *(const float4*)(X + (size_t)node * DH + c)
                              : make_float4(0.f, 0.f, 0.f, 0.f);
        *(float4*)&xs[r * DH + c] = v;
    }
    for (int i = t; i < DH * DH / 4; i += 256) {
        int r = i >> 4, c = (i & 15) * 4;
        *(uint2*)&mlh[r * 68 + c] = ((const uint2*)Mlrh_l)[i];
    }
    __syncthreads();
    int w = t >> 6, lane = t & 63;
    int oc0 = w * 16;
    int rr = lane & 15, g = lane >> 4;
    f32x4 acc = {0.f, 0.f, 0.f, 0.f};
    #pragma unroll
    for (int ks = 0; ks < DH / 16; ++ks) {
        float4 xv = *(const float4*)&xs[rr * DH + ks * 16 + g * 4];
        half4 af = {(__fp16)xv.x, (__fp16)xv.y, (__fp16)xv.z, (__fp16)xv.w};
        half4 bf = *(const half4*)&mlh[(oc0 + rr) * 68 + ks * 16 + g * 4];
        acc = __builtin_amdgcn_mfma_f32_16x16x16f16(af, bf, acc, 0, 0, 0);
    }
    int oc = oc0 + rr;
    #pragma unroll
    for (int r = 0; r < 4; ++r) {
        int node = node0 + g * 4 + r;
        if (node < N) {
            size_t idx = (size_t)node * DH + oc;
            XWf[idx] = acc[r];
            XWh[idx] = (__fp16)acc[r];
        }
    }
}

__global__ __launch_bounds__(256) void k_out(const float* __restrict__ X,
                                             const __fp16* __restrict__ W2h,
                                             const float* __restrict__ b2,
                                             float* __restrict__ out, int N) {
    __shared__ float xs[32 * DH];
    __shared__ __fp16 w2s[OUTC * 68];
    int t = threadIdx.x;
    int node0 = blockIdx.x * 32;
    for (int i = t; i < 32 * DH / 4; i += 256) {
        int r = i >> 4, c = (i & 15) * 4;
        int node = node0 + r;
        float4 v = (node < N) ? *(const float4*)(X + (size_t)node * DH + c)
                              : make_float4(0.f, 0.f, 0.f, 0.f);
        *(float4*)&xs[r * DH + c] = v;
    }
    for (int i = t; i < OUTC * DH / 4; i += 256) {
        int r = i >> 4, c = (i & 15) * 4;
        *(uint2*)&w2s[r * 68 + c] = ((const uint2*)W2h)[i];
    }
    __syncthreads();
    int w = t >> 6, lane = t & 63;
    int nt = w >> 1;
    int oc0 = (w & 1) * 16;
    int rr = lane & 15, g = lane >> 4;
    f32x4 acc = {0.f, 0.f, 0.f, 0.f};
    #pragma unroll
    for (int ks = 0; ks < DH / 16; ++ks) {
        float4 xv = *(const float4*)&xs[(nt * 16 + rr) * DH + ks * 16 + g * 4];
        half4 af = {(__fp16)xv.x, (__fp16)xv.y, (__fp16)xv.z, (__fp16)xv.w};
        half4 bf = *(const half4*)&w2s[(oc0 + rr) * 68 + ks * 16 + g * 4];
        acc = __builtin_amdgcn_mfma_f32_16x16x16f16(af, bf, acc, 0, 0, 0);
    }
    int oc = oc0 + rr;
    float bb = b2[oc];
    #pragma unroll
    for (int r = 0; r < 4; ++r) {
        int node = node0 + nt * 16 + g * 4 + r;
        if (node < N) out[(size_t)node * OUTC + oc] = acc[r] + bb;
    }
}

// ---------------- per-layer edge kernels (no atomics) ----------------

// wave per 4 nodes, 16 lanes/node: DG[u,s] = sum over CSR row of tanh(P_u+Q_v)^2
__global__ void k_dg(const float2* __restrict__ P, const float2* __restrict__ Q,
                     const int* __restrict__ rowptr, const int* __restrict__ csr_dst,
                     float2* __restrict__ DG, int N) {
    int wid = (blockIdx.x * blockDim.x + threadIdx.x) >> 6;
    int lane = threadIdx.x & 63;
    int nn = lane >> 4, sub = lane & 15;
    int node = wid * 4 + nn;
    if (node >= N) return;
    float2 Pu = P[node];
    int pos = rowptr[node], end = rowptr[node + 1];
    float sx = 0.f, sy = 0.f;
    for (int i = pos + sub; i < end; i += 16) {
        int v = csr_dst[i];
        float2 Qv = Q[v];
        float fx = tanhf(Pu.x + Qv.x);
        float fy = tanhf(Pu.y + Qv.y);
        sx += fx * fx;
        sy += fy * fy;
    }
    #pragma unroll
    for (int ofs = 8; ofs; ofs >>= 1) {
        sx += __shfl_xor(sx, ofs);
        sy += __shfl_xor(sy, ofs);
    }
    if (sub == 0) DG[node] = make_float2(sx, sy);
}

// thread per undirected edge: w_e[t] = -tanh(Pu+Qv)*tanh(Pv+Qu)*dinv_u*dinv_v (coalesced write)
__global__ void k_we(const int* __restrict__ src, const int* __restrict__ dst,
                     const float2* __restrict__ P, const float2* __restrict__ Q,
                     const float2* __restrict__ DG, float2* __restrict__ w_e, int EU) {
    int t = blockIdx.x * blockDim.x + threadIdx.x;
    if (t >= EU) return;
    int u = src[t], v = dst[t];
    float2 Pu = P[u], Qv = Q[v], Pv = P[v], Qu = Q[u];
    float2 gu = DG[u], gv = DG[v];
    float ffx = tanhf(Pu.x + Qv.x), ffy = tanhf(Pu.y + Qv.y);
    float fbx = tanhf(Pv.x + Qu.x), fby = tanhf(Pv.y + Qu.y);
    float2 w;
    w.x = -ffx * fbx * rsqrtf(gu.x + 1.f) * rsqrtf(gv.x + 1.f);
    w.y = -ffy * fby * rsqrtf(gu.y + 1.f) * rsqrtf(gv.y + 1.f);
    w_e[t] = w;
}

// wave per node, 4 edge slots x 16 channel lanes; fused elu/residual + next-layer P/Q
__global__ void k_spmm_fin_pq(const float* __restrict__ XWf, const __fp16* __restrict__ XWh,
                              const float2* __restrict__ w_e, const int* __restrict__ rowptr,
                              const int* __restrict__ csr_dst, const int* __restrict__ csr_eu,
                              const float2* __restrict__ DG, const float* __restrict__ eps_l,
                              const float* __restrict__ Wsn, float* __restrict__ X,
                              float2* __restrict__ P, float2* __restrict__ Q, int N) {
    int wid = (blockIdx.x * blockDim.x + threadIdx.x) >> 6;
    int lane = threadIdx.x & 63;
    if (wid >= N) return;
    int q = lane >> 4;        // edge slot 0..3
    int m = lane & 15;        // channel quad
    int s = m >> 3;           // stalk
    int pos = rowptr[wid], end = rowptr[wid + 1];
    float ax = 0.f, ay = 0.f, az = 0.f, aw = 0.f;
    #pragma unroll 2
    for (int base = pos; base < end; base += 4) {
        int idx = base + q;
        bool valid = idx < end;
        int d = 0;
        float wgt = 0.f;
        if (valid) {
            d = csr_dst[idx];
            float2 wv = w_e[csr_eu[idx]];
            wgt = s ? wv.y : wv.x;
        }
        half4 g = *(const half4*)(XWh + (size_t)d * DH + m * 4);
        ax += wgt * (float)g.x;
        ay += wgt * (float)g.y;
        az += wgt * (float)g.z;
        aw += wgt * (float)g.w;
    }
    ax += __shfl_xor(ax, 16); ay += __shfl_xor(ay, 16);
    az += __shfl_xor(az, 16); aw += __shfl_xor(aw, 16);
    ax += __shfl_xor(ax, 32); ay += __shfl_xor(ay, 32);
    az += __shfl_xor(az, 32); aw += __shfl_xor(aw, 32);
    if (q == 0) {
        float2 dgv = DG[wid];
        float dg = s ? dgv.y : dgv.x;
        float diag = dg / (dg + 1.f);
        size_t base_idx = (size_t)wid * DH + m * 4;
        float4 xwf = *(const float4*)(XWf + base_idx);
        float4 y;
        y.x = diag * xwf.x + ax;
        y.y = diag * xwf.y + ay;
        y.z = diag * xwf.z + az;
        y.w = diag * xwf.w + aw;
        float coeff = 1.f + tanhf(eps_l[s]);
        float4 xold = *(const float4*)(X + base_idx);
        float4 xn;
        xn.x = coeff * xold.x - eluf(y.x);
        xn.y = coeff * xold.y - eluf(y.y);
        xn.z = coeff * xold.z - eluf(y.z);
        xn.w = coeff * xold.w - eluf(y.w);
        *(float4*)(X + base_idx) = xn;
        if (Wsn) {
            float4 wa = *(const float4*)(Wsn + m * 4);
            float4 wb = *(const float4*)(Wsn + 64 + m * 4);
            float4 wc = *(const float4*)(Wsn + 128 + m * 4);
            float4 wd = *(const float4*)(Wsn + 192 + m * 4);
            float p0 = xn.x * wa.x + xn.y * wa.y + xn.z * wa.z + xn.w * wa.w;
            float q0 = xn.x * wb.x + xn.y * wb.y + xn.z * wb.z + xn.w * wb.w;
            float p1 = xn.x * wc.x + xn.y * wc.y + xn.z * wc.z + xn.w * wc.w;
            float q1 = xn.x * wd.x + xn.y * wd.y + xn.z * wd.z + xn.w * wd.w;
            #pragma unroll
            for (int ofs = 8; ofs; ofs >>= 1) {
                p0 += __shfl_xor(p0, ofs);
                q0 += __shfl_xor(q0, ofs);
                p1 += __shfl_xor(p1, ofs);
                q1 += __shfl_xor(q1, ofs);
            }
            if (m == 0) {
                P[wid] = make_float2(p0, p1);
                Q[wid] = make_float2(q0, q1);
            }
        }
    }
}

extern "C" void kernel_launch(void* const* d_in, const int* in_sizes, int n_in,
                              void* d_out, int out_size, void* d_ws, size_t ws_size,
                              hipStream_t stream) {
    const float* xin    = (const float*)d_in[0];
    const int*   ei     = (const int*)d_in[1];
    const float* W1     = (const float*)d_in[2];
    const float* b1     = (const float*)d_in[3];
    const float* Wsheaf = (const float*)d_in[4];
    const float* Wleft  = (const float*)d_in[5];
    const float* Wright = (const float*)d_in[6];
    const float* eps    = (const float*)d_in[7];
    const float* W2     = (const float*)d_in[8];
    const float* b2     = (const float*)d_in[9];
    float* out = (float*)d_out;

    int N = in_sizes[0] / INCH;
    int E = in_sizes[1] / 2;
    int EU = E / 2;
    const int* src = ei;
    const int* dst = ei + E;

    size_t off = 0;
    auto alloc = [&](size_t nbytes) {
        char* p = (char*)d_ws + off;
        off += (nbytes + 255) & ~(size_t)255;
        return p;
    };
    float*   X       = (float*)alloc((size_t)N * DH * 4);
    float*   XWf     = (float*)alloc((size_t)N * DH * 4);
    __fp16*  XWh     = (__fp16*)alloc((size_t)N * DH * 2);
    float2*  w_e     = (float2*)alloc((size_t)EU * 8);
    float2*  DG      = (float2*)alloc((size_t)N * 8);
    float2*  P       = (float2*)alloc((size_t)N * 8);
    float2*  Q       = (float2*)alloc((size_t)N * 8);
    int*     deg     = (int*)alloc((size_t)N * 4);
    int*     rowptr  = (int*)alloc(((size_t)N + 1) * 4);
    int*     cur     = (int*)alloc((size_t)N * 4);
    int*     csr_dst = (int*)alloc((size_t)E * 4);
    int*     csr_eu  = (int*)alloc((size_t)E * 4);
    __fp16*  W1h     = (__fp16*)alloc((size_t)DH * INCH * 2);
    __fp16*  W2h     = (__fp16*)alloc((size_t)OUTC * DH * 2);
    __fp16*  Mlrh    = (__fp16*)alloc((size_t)LAYERS * DH * DH * 2);

    // one-time prep + CSR build
    int prep_total = DH * INCH + OUTC * DH + LAYERS * DH * DH;
    k_prep<<<(prep_total + 255) / 256, 256, 0, stream>>>(W1, W2, Wleft, Wright, W1h, W2h, Mlrh);
    hipMemsetAsync(deg, 0, (size_t)N * sizeof(int), stream);
    k_hist<<<(E + 255) / 256, 256, 0, stream>>>(src, deg, E);
    k_scan<<<1, 1024, 0, stream>>>(deg, rowptr, N);
    k_initcur<<<(N + 255) / 256, 256, 0, stream>>>(rowptr, cur, N);
    k_scatter<<<(E + 255) / 256, 256, 0, stream>>>(src, dst, cur, csr_dst, csr_eu, E);

    k_mlp1<<<(N + 15) / 16, 256, 0, stream>>>(xin, W1h, b1, X, N);
    k_pq<<<(N + 3) / 4, 256, 0, stream>>>(X, Wsheaf, P, Q, N);

    for (int l = 0; l < LAYERS; ++l) {
        k_dg<<<(N + 15) / 16, 256, 0, stream>>>(P, Q, rowptr, csr_dst, DG, N);
        k_we<<<(EU + 255) / 256, 256, 0, stream>>>(src, dst, P, Q, DG, w_e, EU);
        k_lr<<<(N + 15) / 16, 256, 0, stream>>>(X, Mlrh + (size_t)l * DH * DH, XWf, XWh, N);
        const float* Wsn = (l + 1 < LAYERS) ? (Wsheaf + (l + 1) * 2 * INCH) : nullptr;
        k_spmm_fin_pq<<<(N + 3) / 4, 256, 0, stream>>>(XWf, XWh, w_e, rowptr, csr_dst, csr_eu,
                                                       DG, eps + l * 2, Wsn, X, P, Q, N);
    }

    k_out<<<(N + 31) / 32, 256, 0, stream>>>(X, W2h, b2, out, N);
}